// Round 3
// 235.797 us; speedup vs baseline: 1.0341x; 1.0341x over previous
//
#include <hip/hip_runtime.h>
#include <hip/hip_bf16.h>

#define Bz 64
#define Tz 512
#define Dz 1024
#define Kz 32

#define MOFF 128
#define LOFF (128 + 1024 * 1024)

typedef __attribute__((ext_vector_type(8)))  __bf16 bf16x8;
typedef __attribute__((ext_vector_type(16))) float  f32x16;

__device__ __forceinline__ float bcast_lane(float x, int i) {
    return __uint_as_float(__builtin_amdgcn_readlane(__float_as_uint(x), i));
}

// pack two f32 into bf16x2 (lo -> bits 0..15, hi -> bits 16..31), round-half-up
__device__ __forceinline__ unsigned pack2bf(float lo, float hi) {
    return __builtin_amdgcn_perm(__float_as_uint(hi) + 0x8000u,
                                 __float_as_uint(lo) + 0x8000u, 0x07060302u);
}

union BfCast { unsigned u[4]; bf16x8 v; };

// ---------------------------------------------------------------------------
// Fused kernel 1+2a: logits tile via bf16 MFMA 32x32x16, then the per-(b,seg)
// 32x32 CRF transfer-matrix chain on the SAME tile (wave 0), sharing the tile
// through LDS. Saves one 1024-block launch, the 4.2 MB logits round-trip and
// its exposed load latency, and halves exp count (each logit exp'd once).
// 1024 blocks x 256 thr; waves 1-3 exit after the partial-C combine write.
// __launch_bounds__(256,3) pins VGPR so occupancy stays 3 blocks/CU.
// ---------------------------------------------------------------------------
__global__ __launch_bounds__(256, 3) void logits_seg_kernel(
        const float* __restrict__ V, const float* __restrict__ W,
        const float* __restrict__ bias, const float* __restrict__ trans,
        float* __restrict__ out, float* __restrict__ ws) {
    __shared__ float part[3][16][64];   // 12 KB  K-quarter partials
    __shared__ float evs[32 * 32];      // 4 KB   exp(logits) tile
    __shared__ float xpose[33 * 32];    // 4.2 KB transpose staging

    const int tid  = threadIdx.x;
    const int wv   = tid >> 6;          // K-quarter index
    const int lane = tid & 63;
    const int n    = lane & 31;
    const int h    = lane >> 5;
    const int bid  = blockIdx.x;
    const int r0   = bid * 32;

    const float* arow = V + (size_t)(r0 + n) * Dz + wv * 256 + h * 8;

    // V prefetch ring first (covers W-load latency too)
    float4 pf[4][2];
    #pragma unroll
    for (int s = 0; s < 4; ++s) {
        pf[s][0] = *(const float4*)(arow + s * 16);
        pf[s][1] = *(const float4*)(arow + s * 16 + 4);
    }

    // preload this wave's W B-frags: 16 kb x 4 VGPR (bf16-packed)
    const float* wrow = W + (size_t)n * Dz + wv * 256 + h * 8;
    BfCast wf[16];
    #pragma unroll
    for (int kb = 0; kb < 16; ++kb) {
        const float4 w0 = *(const float4*)(wrow + kb * 16);
        const float4 w1 = *(const float4*)(wrow + kb * 16 + 4);
        wf[kb].u[0] = pack2bf(w0.x, w0.y);
        wf[kb].u[1] = pack2bf(w0.z, w0.w);
        wf[kb].u[2] = pack2bf(w1.x, w1.y);
        wf[kb].u[3] = pack2bf(w1.z, w1.w);
    }

    f32x16 acc;
    #pragma unroll
    for (int i = 0; i < 16; ++i) acc[i] = 0.f;

    #pragma unroll
    for (int kb = 0; kb < 16; ++kb) {
        const float4 a0 = pf[kb & 3][0];
        const float4 a1 = pf[kb & 3][1];
        if (kb + 4 < 16) {
            pf[kb & 3][0] = *(const float4*)(arow + (kb + 4) * 16);
            pf[kb & 3][1] = *(const float4*)(arow + (kb + 4) * 16 + 4);
        }
        BfCast cA;
        cA.u[0] = pack2bf(a0.x, a0.y);
        cA.u[1] = pack2bf(a0.z, a0.w);
        cA.u[2] = pack2bf(a1.x, a1.y);
        cA.u[3] = pack2bf(a1.z, a1.w);
        acc = __builtin_amdgcn_mfma_f32_32x32x16_bf16(cA.v, wf[kb].v, acc, 0, 0, 0);
    }

    // combine the 4 K-quarter partials; waves 1-3 are done after this
    if (wv > 0) {
        #pragma unroll
        for (int i = 0; i < 16; ++i) part[wv - 1][i][lane] = acc[i];
    }
    __syncthreads();
    if (wv != 0) return;

    // ---- wave 0: finalize logits, write out, exp into LDS ----
    int rIdx[16];
    #pragma unroll
    for (int i = 0; i < 16; ++i) rIdx[i] = (i & 3) + 8 * (i >> 2) + 4 * h;

    const float bv = bias[n];
    #pragma unroll
    for (int i = 0; i < 16; ++i) {
        const float s = ((acc[i] + part[0][i][lane]) +
                         (part[1][i][lane] + part[2][i][lane])) + bv;
        out[(size_t)(r0 + rIdx[i]) * Kz + n] = s;     // C/D layout row
        evs[rIdx[i] * 32 + n] = __expf(s);
    }
    __builtin_amdgcn_wave_barrier();   // keep ds_writes before the ds_reads
    // (DS pipe is in-order per wave; compiler inserts the lgkmcnt data waits)

    // ---- seg chain: X <- (diag(E_u)*ET^T) * X, rescale every 8 steps ----
    const int seg = bid & 15;

    float etf[16];
    #pragma unroll
    for (int i = 0; i < 16; ++i) etf[i] = __expf(trans[rIdx[i] * Kz + n]);

    float Ev[32];
    #pragma unroll
    for (int u = 0; u < 32; ++u) Ev[u] = evs[u * 32 + n];

    unsigned bu[8];
    #pragma unroll
    for (int q = 0; q < 4; ++q) {
        bu[q] = ((rIdx[2 * q] == n) ? 0x3F80u : 0u) |
                (((rIdx[2 * q + 1] == n) ? 0x3F80u : 0u) << 16);
        bu[4 + q] = ((rIdx[8 + 2 * q] == n) ? 0x3F80u : 0u) |
                    (((rIdx[8 + 2 * q + 1] == n) ? 0x3F80u : 0u) << 16);
    }

    f32x16 zf;
    #pragma unroll
    for (int i = 0; i < 16; ++i) zf[i] = 0.f;

    float Xs[16];
    #pragma unroll
    for (int i = 0; i < 16; ++i) Xs[i] = (rIdx[i] == n) ? 1.f : 0.f;
    float lsc = 0.f;

    #pragma unroll
    for (int u = 0; u < 32; ++u) {
        if (u > 0 || seg > 0) {
            const float E = Ev[u];
            BfCast cA1, cA2, cB1, cB2;
            #pragma unroll
            for (int q = 0; q < 4; ++q) {
                cA1.u[q] = pack2bf(E * etf[2 * q], E * etf[2 * q + 1]);
                cA2.u[q] = pack2bf(E * etf[8 + 2 * q], E * etf[8 + 2 * q + 1]);
                cB1.u[q] = bu[q];
                cB2.u[q] = bu[4 + q];
            }
            f32x16 a2 = __builtin_amdgcn_mfma_f32_32x32x16_bf16(cA1.v, cB1.v, zf, 0, 0, 0);
            a2 = __builtin_amdgcn_mfma_f32_32x32x16_bf16(cA2.v, cB2.v, a2, 0, 0, 0);
            #pragma unroll
            for (int i = 0; i < 16; ++i) Xs[i] = a2[i];
            if ((u & 7) == 7) {   // uniform rescale (hits u==31 -> stored P bounded)
                float m = Xs[0];
                #pragma unroll
                for (int i = 1; i < 16; ++i) m = fmaxf(m, Xs[i]);
                #pragma unroll
                for (int dd = 1; dd < 64; dd <<= 1) m = fmaxf(m, __shfl_xor(m, dd, 64));
                const float r = __builtin_amdgcn_rcpf(m);
                lsc += __logf(m);
                #pragma unroll
                for (int i = 0; i < 16; ++i) Xs[i] *= r;
            }
            #pragma unroll
            for (int q = 0; q < 4; ++q) {
                bu[q]     = pack2bf(Xs[2 * q], Xs[2 * q + 1]);
                bu[4 + q] = pack2bf(Xs[8 + 2 * q], Xs[8 + 2 * q + 1]);
            }
        }
    }

    // transpose through LDS so the P write is coalesced
    #pragma unroll
    for (int i = 0; i < 16; ++i)
        xpose[n * 33 + rIdx[i]] = Xs[i];
    __builtin_amdgcn_wave_barrier();
    float* mout = ws + MOFF + (size_t)bid * 1024;
    #pragma unroll
    for (int k = 0; k < 16; ++k) {
        const int row = 2 * k + h;
        mout[row * 32 + n] = xpose[row * 33 + n];
    }
    if (lane == 0) ws[LOFF + bid] = lsc;
}

// ---------------------------------------------------------------------------
// Kernel 2b: combine — alpha through 16 segment matrices + gold score.
// 64 blocks x 64 threads. P prefetched one segment ahead; the 16 per-segment
// log-scale values preloaded into one lane-indexed register (readlane bcast)
// instead of 16 latency-exposed scalar loads inside the dependent chain.
// ---------------------------------------------------------------------------
__global__ __launch_bounds__(64) void crf_combine_kernel(
        const float* __restrict__ logits, const int* __restrict__ mask,
        const int* __restrict__ targets, const float* __restrict__ trans,
        const float* __restrict__ start_t, const float* __restrict__ end_t,
        float* __restrict__ ws) {
    const int b    = blockIdx.x;
    const int lane = threadIdx.x;
    const int n    = lane & 31;

    const float* lg = logits + (size_t)b * Tz * Kz;
    const int*   tg = targets + b * Tz;
    const int*   mk = mask + b * Tz;

    // all 16 per-segment log-scales up front (lane i holds segment i's value)
    float lscv = (lane < 16) ? ws[LOFF + b * 16 + lane] : 0.f;

    float emit_s = 0.f, trans_s = 0.f, msum = 0.f;
    for (int t = lane; t < Tz; t += 64) {
        const int   tt = tg[t];
        const float m  = (float)mk[t];
        emit_s += lg[t * Kz + tt] * m;
        if (t > 0) trans_s += trans[tg[t - 1] * Kz + tt] * m;
        msum += m;
    }
    float ssum = emit_s + trans_s;
    #pragma unroll
    for (int dd = 1; dd < 64; dd <<= 1) {
        ssum += __shfl_xor(ssum, dd, 64);
        msum += __shfl_xor(msum, dd, 64);
    }

    float al = start_t[n] + lg[n];
    float m0 = al;
    #pragma unroll
    for (int dd = 1; dd < 32; dd <<= 1) m0 = fmaxf(m0, __shfl_xor(m0, dd, 64));
    float v    = __expf(al - m0);
    float lacc = m0;

    const float* Pb = ws + MOFF + (size_t)b * 16 * 1024;
    float pv[32];
    #pragma unroll
    for (int i = 0; i < 32; ++i) pv[i] = Pb[i * 32 + n];

    #pragma unroll
    for (int s = 0; s < 16; ++s) {
        float pn[32];
        if (s + 1 < 16) {
            const float* Pn = Pb + (size_t)(s + 1) * 1024;
            #pragma unroll
            for (int i = 0; i < 32; ++i) pn[i] = Pn[i * 32 + n];
        }
        float n0 = 0.f, n1 = 0.f, n2 = 0.f, n3 = 0.f;
        #pragma unroll
        for (int i = 0; i < 32; i += 4) {
            n0 = fmaf(bcast_lane(v, i + 0), pv[i + 0], n0);
            n1 = fmaf(bcast_lane(v, i + 1), pv[i + 1], n1);
            n2 = fmaf(bcast_lane(v, i + 2), pv[i + 2], n2);
            n3 = fmaf(bcast_lane(v, i + 3), pv[i + 3], n3);
        }
        v = (n0 + n1) + (n2 + n3);
        lacc += bcast_lane(lscv, s);
        float mm = v;
        #pragma unroll
        for (int dd = 1; dd < 32; dd <<= 1) mm = fmaxf(mm, __shfl_xor(mm, dd, 64));
        v *= __builtin_amdgcn_rcpf(mm);
        lacc += __logf(mm);
        if (s + 1 < 16) {
            #pragma unroll
            for (int i = 0; i < 32; ++i) pv[i] = pn[i];
        }
    }

    float w  = v * __expf(end_t[n]);
    float sv = w;
    #pragma unroll
    for (int dd = 1; dd < 32; dd <<= 1) sv += __shfl_xor(sv, dd, 64);
    const float part = lacc + __logf(sv);

    if (lane == 0) {
        const int lastIdx = (int)msum - 1;
        const float score = start_t[tg[0]] + ssum + end_t[tg[lastIdx]];
        ws[b]      = score - part;
        ws[64 + b] = msum;
    }
}

// ---------------------------------------------------------------------------
// Kernel 3: loss = -sum_b(score_b - part_b) / sum(mask)
// ---------------------------------------------------------------------------
__global__ __launch_bounds__(64) void crf_final_kernel(
        const float* __restrict__ ws, float* __restrict__ out) {
    const int lane = threadIdx.x;
    float p    = ws[lane];
    float msum = ws[64 + lane];
    #pragma unroll
    for (int dd = 1; dd < 64; dd <<= 1) {
        p    += __shfl_xor(p, dd, 64);
        msum += __shfl_xor(msum, dd, 64);
    }
    if (lane == 0) out[0] = -p / msum;
}

extern "C" void kernel_launch(void* const* d_in, const int* in_sizes, int n_in,
                              void* d_out, int out_size, void* d_ws, size_t ws_size,
                              hipStream_t stream) {
    const float* V       = (const float*)d_in[0];
    const int*   mask    = (const int*)d_in[1];
    const int*   targets = (const int*)d_in[2];
    const float* W       = (const float*)d_in[3];
    const float* bias    = (const float*)d_in[4];
    const float* trans   = (const float*)d_in[5];
    const float* start_t = (const float*)d_in[6];
    const float* end_t   = (const float*)d_in[7];

    float* out = (float*)d_out;   // out[0] = loss, out[1..] = logits [B,T,K]
    float* ws  = (float*)d_ws;    // ~4.2 MB used

    logits_seg_kernel<<<1024, 256, 0, stream>>>(V, W, bias, trans, out + 1, ws);
    crf_combine_kernel<<<64, 64, 0, stream>>>(out + 1, mask, targets, trans,
                                              start_t, end_t, ws);
    crf_final_kernel<<<1, 64, 0, stream>>>(ws, out);
}

// Round 4
// 230.700 us; speedup vs baseline: 1.0570x; 1.0221x over previous
//
#include <hip/hip_runtime.h>
#include <hip/hip_bf16.h>

#define Bz 64
#define Tz 512
#define Dz 1024
#define Kz 32

#define MOFF 128
#define LOFF (128 + 1024 * 1024)

typedef __attribute__((ext_vector_type(8)))  __bf16 bf16x8;
typedef __attribute__((ext_vector_type(16))) float  f32x16;

__device__ __forceinline__ float bcast_lane(float x, int i) {
    return __uint_as_float(__builtin_amdgcn_readlane(__float_as_uint(x), i));
}

// pack two f32 into bf16x2 (lo -> bits 0..15, hi -> bits 16..31), round-half-up
__device__ __forceinline__ unsigned pack2bf(float lo, float hi) {
    return __builtin_amdgcn_perm(__float_as_uint(hi) + 0x8000u,
                                 __float_as_uint(lo) + 0x8000u, 0x07060302u);
}

union BfCast { unsigned u[4]; bf16x8 v; };

// ---------------------------------------------------------------------------
// Fused kernel 1+2a: logits tile via bf16 MFMA 32x32x16, then the per-(b,seg)
// 32x32 CRF transfer-matrix chain on the SAME tile (wave 0), sharing the tile
// through LDS. 1024 blocks x 256 thr; waves 1-3 exit after partial-C combine.
// Also zero-inits the 3 global accumulator words used by the fused
// combine+final (ws re-poisoned each iteration, so init must be per-launch).
// ---------------------------------------------------------------------------
__global__ __launch_bounds__(256, 3) void logits_seg_kernel(
        const float* __restrict__ V, const float* __restrict__ W,
        const float* __restrict__ bias, const float* __restrict__ trans,
        float* __restrict__ out, float* __restrict__ ws) {
    __shared__ float part[3][16][64];   // 12 KB  K-quarter partials
    __shared__ float evs[32 * 32];      // 4 KB   exp(logits) tile
    __shared__ float xpose[33 * 32];    // 4.2 KB transpose staging

    const int tid  = threadIdx.x;
    const int wv   = tid >> 6;          // K-quarter index
    const int lane = tid & 63;
    const int n    = lane & 31;
    const int h    = lane >> 5;
    const int bid  = blockIdx.x;
    const int r0   = bid * 32;

    if (bid == 0 && tid == 0) {         // accumulators for fused combine+final
        ws[96] = 0.f; ws[97] = 0.f; ws[98] = 0.f;
    }

    const float* arow = V + (size_t)(r0 + n) * Dz + wv * 256 + h * 8;

    // V prefetch ring first (covers W-load latency too)
    float4 pf[4][2];
    #pragma unroll
    for (int s = 0; s < 4; ++s) {
        pf[s][0] = *(const float4*)(arow + s * 16);
        pf[s][1] = *(const float4*)(arow + s * 16 + 4);
    }

    // preload this wave's W B-frags: 16 kb x 4 VGPR (bf16-packed)
    const float* wrow = W + (size_t)n * Dz + wv * 256 + h * 8;
    BfCast wf[16];
    #pragma unroll
    for (int kb = 0; kb < 16; ++kb) {
        const float4 w0 = *(const float4*)(wrow + kb * 16);
        const float4 w1 = *(const float4*)(wrow + kb * 16 + 4);
        wf[kb].u[0] = pack2bf(w0.x, w0.y);
        wf[kb].u[1] = pack2bf(w0.z, w0.w);
        wf[kb].u[2] = pack2bf(w1.x, w1.y);
        wf[kb].u[3] = pack2bf(w1.z, w1.w);
    }

    f32x16 acc;
    #pragma unroll
    for (int i = 0; i < 16; ++i) acc[i] = 0.f;

    #pragma unroll
    for (int kb = 0; kb < 16; ++kb) {
        const float4 a0 = pf[kb & 3][0];
        const float4 a1 = pf[kb & 3][1];
        if (kb + 4 < 16) {
            pf[kb & 3][0] = *(const float4*)(arow + (kb + 4) * 16);
            pf[kb & 3][1] = *(const float4*)(arow + (kb + 4) * 16 + 4);
        }
        BfCast cA;
        cA.u[0] = pack2bf(a0.x, a0.y);
        cA.u[1] = pack2bf(a0.z, a0.w);
        cA.u[2] = pack2bf(a1.x, a1.y);
        cA.u[3] = pack2bf(a1.z, a1.w);
        acc = __builtin_amdgcn_mfma_f32_32x32x16_bf16(cA.v, wf[kb].v, acc, 0, 0, 0);
    }

    // combine the 4 K-quarter partials; waves 1-3 are done after this
    if (wv > 0) {
        #pragma unroll
        for (int i = 0; i < 16; ++i) part[wv - 1][i][lane] = acc[i];
    }
    __syncthreads();
    if (wv != 0) return;

    // ---- wave 0: finalize logits, write out, exp into LDS ----
    int rIdx[16];
    #pragma unroll
    for (int i = 0; i < 16; ++i) rIdx[i] = (i & 3) + 8 * (i >> 2) + 4 * h;

    const float bv = bias[n];
    #pragma unroll
    for (int i = 0; i < 16; ++i) {
        const float s = ((acc[i] + part[0][i][lane]) +
                         (part[1][i][lane] + part[2][i][lane])) + bv;
        out[(size_t)(r0 + rIdx[i]) * Kz + n] = s;     // C/D layout row
        evs[rIdx[i] * 32 + n] = __expf(s);
    }
    __builtin_amdgcn_wave_barrier();   // keep ds_writes before the ds_reads

    // ---- seg chain: X <- (diag(E_u)*ET^T) * X, rescale every 8 steps ----
    const int seg = bid & 15;

    float etf[16];
    #pragma unroll
    for (int i = 0; i < 16; ++i) etf[i] = __expf(trans[rIdx[i] * Kz + n]);

    float Ev[32];
    #pragma unroll
    for (int u = 0; u < 32; ++u) Ev[u] = evs[u * 32 + n];

    unsigned bu[8];
    #pragma unroll
    for (int q = 0; q < 4; ++q) {
        bu[q] = ((rIdx[2 * q] == n) ? 0x3F80u : 0u) |
                (((rIdx[2 * q + 1] == n) ? 0x3F80u : 0u) << 16);
        bu[4 + q] = ((rIdx[8 + 2 * q] == n) ? 0x3F80u : 0u) |
                    (((rIdx[8 + 2 * q + 1] == n) ? 0x3F80u : 0u) << 16);
    }

    f32x16 zf;
    #pragma unroll
    for (int i = 0; i < 16; ++i) zf[i] = 0.f;

    float Xs[16];
    #pragma unroll
    for (int i = 0; i < 16; ++i) Xs[i] = (rIdx[i] == n) ? 1.f : 0.f;
    float lsc = 0.f;

    #pragma unroll
    for (int u = 0; u < 32; ++u) {
        if (u > 0 || seg > 0) {
            const float E = Ev[u];
            BfCast cA1, cA2, cB1, cB2;
            #pragma unroll
            for (int q = 0; q < 4; ++q) {
                cA1.u[q] = pack2bf(E * etf[2 * q], E * etf[2 * q + 1]);
                cA2.u[q] = pack2bf(E * etf[8 + 2 * q], E * etf[8 + 2 * q + 1]);
                cB1.u[q] = bu[q];
                cB2.u[q] = bu[4 + q];
            }
            f32x16 a2 = __builtin_amdgcn_mfma_f32_32x32x16_bf16(cA1.v, cB1.v, zf, 0, 0, 0);
            a2 = __builtin_amdgcn_mfma_f32_32x32x16_bf16(cA2.v, cB2.v, a2, 0, 0, 0);
            #pragma unroll
            for (int i = 0; i < 16; ++i) Xs[i] = a2[i];
            if ((u & 7) == 7) {   // uniform rescale (hits u==31 -> stored P bounded)
                float m = Xs[0];
                #pragma unroll
                for (int i = 1; i < 16; ++i) m = fmaxf(m, Xs[i]);
                #pragma unroll
                for (int dd = 1; dd < 64; dd <<= 1) m = fmaxf(m, __shfl_xor(m, dd, 64));
                const float r = __builtin_amdgcn_rcpf(m);
                lsc += __logf(m);
                #pragma unroll
                for (int i = 0; i < 16; ++i) Xs[i] *= r;
            }
            #pragma unroll
            for (int q = 0; q < 4; ++q) {
                bu[q]     = pack2bf(Xs[2 * q], Xs[2 * q + 1]);
                bu[4 + q] = pack2bf(Xs[8 + 2 * q], Xs[8 + 2 * q + 1]);
            }
        }
    }

    // transpose through LDS so the P write is coalesced
    #pragma unroll
    for (int i = 0; i < 16; ++i)
        xpose[n * 33 + rIdx[i]] = Xs[i];
    __builtin_amdgcn_wave_barrier();
    float* mout = ws + MOFF + (size_t)bid * 1024;
    #pragma unroll
    for (int k = 0; k < 16; ++k) {
        const int row = 2 * k + h;
        mout[row * 32 + n] = xpose[row * 33 + n];
    }
    if (lane == 0) ws[LOFF + bid] = lsc;
}

// ---------------------------------------------------------------------------
// Fused kernel 2b+3: combine + final. 64 blocks x 256 threads.
//  - all 4 waves stage P segs 1..15 into LDS via global_load_lds (width 16,
//    identity layout, 60 KB) -- chain reads LDS instead of latency-exposed
//    global loads; seg 0 preloaded to wave-0 registers before the barrier.
//  - wave 1 computes the gold score CONCURRENTLY with wave 0's alpha chain.
//  - per-batch result folded via device-scope f32 atomics; the last block
//    (atomic counter) writes the loss. Accumulators (ws[96..98]) are
//    zero-inited by logits_seg each launch -> re-poison safe. No spin.
// ---------------------------------------------------------------------------
__global__ __launch_bounds__(256) void crf_combine_kernel(
        const float* __restrict__ logits, const int* __restrict__ mask,
        const int* __restrict__ targets, const float* __restrict__ trans,
        const float* __restrict__ start_t, const float* __restrict__ end_t,
        float* __restrict__ ws, float* __restrict__ loss) {
    __shared__ float Plds[15 * 1024];   // 60 KB: segments 1..15
    __shared__ float gshare[2];         // gold score, msum

    const int b    = blockIdx.x;
    const int tid  = threadIdx.x;
    const int wv   = tid >> 6;
    const int lane = tid & 63;
    const int n    = lane & 31;

    const float* Pb = ws + MOFF + (size_t)b * 16 * 1024;

    // stage segs 1..15 (wave wv covers 1+4wv .. 4+4wv); 16B/lane, 1KB/instr
    #pragma unroll
    for (int ss = 0; ss < 4; ++ss) {
        const int s = 1 + wv * 4 + ss;
        if (s < 16) {
            const float* src = Pb + (s << 10) + (lane << 2);
            #pragma unroll
            for (int c = 0; c < 4; ++c) {
                __builtin_amdgcn_global_load_lds(
                    (const __attribute__((address_space(1))) void*)(src + (c << 8)),
                    (__attribute__((address_space(3))) void*)&Plds[((s - 1) << 10) + (c << 8)],
                    16, 0, 0);
            }
        }
    }

    // wave-0 pre-barrier work: seg-0 P, per-seg log-scales, alpha init
    float pv[32];
    float lscv = 0.f, al = 0.f;
    if (wv == 0) {
        #pragma unroll
        for (int i = 0; i < 32; ++i) pv[i] = Pb[(i << 5) + n];
        lscv = (lane < 16) ? ws[LOFF + b * 16 + lane] : 0.f;
        al = start_t[n] + logits[(size_t)b * Tz * Kz + n];
    }

    __syncthreads();   // LDS P ready (drains vmcnt incl. global_load_lds)

    if (wv == 1) {
        // ---- gold score of the target sequence (concurrent with chain) ----
        const float* lg = logits + (size_t)b * Tz * Kz;
        const int*   tg = targets + b * Tz;
        const int*   mk = mask + b * Tz;

        float emit_s = 0.f, trans_s = 0.f, msum = 0.f;
        for (int t = lane; t < Tz; t += 64) {
            const int   tt = tg[t];
            const float m  = (float)mk[t];
            emit_s += lg[t * Kz + tt] * m;
            if (t > 0) trans_s += trans[tg[t - 1] * Kz + tt] * m;
            msum += m;
        }
        float ssum = emit_s + trans_s;
        #pragma unroll
        for (int dd = 1; dd < 64; dd <<= 1) {
            ssum += __shfl_xor(ssum, dd, 64);
            msum += __shfl_xor(msum, dd, 64);
        }
        if (lane == 0) {
            const int lastIdx = (int)msum - 1;
            gshare[0] = start_t[tg[0]] + ssum + end_t[tg[lastIdx]];
            gshare[1] = msum;
        }
    }

    float part = 0.f;
    if (wv == 0) {
        // ---- alpha through the 16 segment matrices (P from regs/LDS) ----
        float m0 = al;
        #pragma unroll
        for (int dd = 1; dd < 32; dd <<= 1) m0 = fmaxf(m0, __shfl_xor(m0, dd, 64));
        float v    = __expf(al - m0);
        float lacc = m0;

        #pragma unroll
        for (int s = 0; s < 16; ++s) {
            float pn[32];
            if (s + 1 < 16) {   // seg s+1 lives at Plds[s<<10]
                #pragma unroll
                for (int i = 0; i < 32; ++i) pn[i] = Plds[(s << 10) + (i << 5) + n];
            }
            float n0 = 0.f, n1 = 0.f, n2 = 0.f, n3 = 0.f;
            #pragma unroll
            for (int i = 0; i < 32; i += 4) {
                n0 = fmaf(bcast_lane(v, i + 0), pv[i + 0], n0);
                n1 = fmaf(bcast_lane(v, i + 1), pv[i + 1], n1);
                n2 = fmaf(bcast_lane(v, i + 2), pv[i + 2], n2);
                n3 = fmaf(bcast_lane(v, i + 3), pv[i + 3], n3);
            }
            v = (n0 + n1) + (n2 + n3);
            lacc += bcast_lane(lscv, s);
            float mm = v;
            #pragma unroll
            for (int dd = 1; dd < 32; dd <<= 1) mm = fmaxf(mm, __shfl_xor(mm, dd, 64));
            v *= __builtin_amdgcn_rcpf(mm);
            lacc += __logf(mm);
            if (s + 1 < 16) {
                #pragma unroll
                for (int i = 0; i < 32; ++i) pv[i] = pn[i];
            }
        }

        float w  = v * __expf(end_t[n]);
        float sv = w;
        #pragma unroll
        for (int dd = 1; dd < 32; dd <<= 1) sv += __shfl_xor(sv, dd, 64);
        part = lacc + __logf(sv);
    }

    __syncthreads();   // gshare ready for wave 0

    if (wv == 0 && lane == 0) {
        atomicAdd(ws + 96, gshare[0] - part);   // sum_b (score - partition)
        atomicAdd(ws + 97, gshare[1]);          // sum_b msum
        __threadfence();
        const unsigned old = atomicAdd((unsigned*)(ws + 98), 1u);
        if (old == 63u) {                       // last block finalizes loss
            __threadfence();
            const float p = atomicAdd(ws + 96, 0.f);
            const float m = atomicAdd(ws + 97, 0.f);
            loss[0] = -p / m;
        }
    }
}

extern "C" void kernel_launch(void* const* d_in, const int* in_sizes, int n_in,
                              void* d_out, int out_size, void* d_ws, size_t ws_size,
                              hipStream_t stream) {
    const float* V       = (const float*)d_in[0];
    const int*   mask    = (const int*)d_in[1];
    const int*   targets = (const int*)d_in[2];
    const float* W       = (const float*)d_in[3];
    const float* bias    = (const float*)d_in[4];
    const float* trans   = (const float*)d_in[5];
    const float* start_t = (const float*)d_in[6];
    const float* end_t   = (const float*)d_in[7];

    float* out = (float*)d_out;   // out[0] = loss, out[1..] = logits [B,T,K]
    float* ws  = (float*)d_ws;    // ~4.2 MB used

    logits_seg_kernel<<<1024, 256, 0, stream>>>(V, W, bias, trans, out + 1, ws);
    crf_combine_kernel<<<64, 256, 0, stream>>>(out + 1, mask, targets, trans,
                                               start_t, end_t, ws, out);
}